// Round 1
// baseline (644.512 us; speedup 1.0000x reference)
//
#include <hip/hip_runtime.h>

// Problem constants (match the JAX reference).
constexpr int Zd = 224;
constexpr int Yd = 512;
constexpr int Xd = 512;
constexpr int Pd = 15;          // spectral predictors
constexpr int WDIM = Pd + 4;    // 19 weights per band
constexpr float MAXV = 32767.0f;   // 2^15 - 1
constexpr float MINV = -32768.0f;  // -2^15

constexpr int NCHUNK = 4;            // z-chunks (parallelism: 4 blocks/CU)
constexpr int CHUNK  = Zd / NCHUNK;  // 56 bands per chunk

typedef float v4f __attribute__((ext_vector_type(4)));

// Outputs (preds, resids) depend only on image and the INPUT weights (the
// scan's weight update for band z is never read by any other band's output).
//
// pred[z,y,x] = clip( cn*north + cw*west + cnw*nw
//                     + sum_{k=0..14} w[4+k]*image[z-15+k,y,x] )
// with cn = w0 + w3/3 etc. (folding the "fourth" predictor).
//
// Rolling-window kernel: thread owns (y, x..x+3), marches z through its
// chunk keeping the previous 15 bands' self-values in registers.
//
// This revision adds:
//  - depth-1 register prefetch of band z+1 (self/north/edges) issued BEFORE
//    band z's FMA chain, so the vmcnt wait overlaps ~330 cyc of compute x
//    4 waves/SIMD instead of serializing load->use every band;
//  - nontemporal stores for preds/resids (pure streaming, zero reuse) so the
//    470 MB write stream stops evicting image bands from L2 that the
//    north-reads and next chunk's window preloads want to hit;
//  - unroll-2 on the z-loop so regalloc renames the rolling window across
//    iterations (halves the 56 v_mov/iter shift cost).
__global__ __launch_bounds__(256, 4) void spec_pred_roll(
    const float* __restrict__ image,
    const float* __restrict__ weights,
    float* __restrict__ preds,
    float* __restrict__ resids)
{
    const int y  = blockIdx.y * 2 + threadIdx.y;   // blockDim = (128, 2)
    const int x  = threadIdx.x * 4;                // 128 threads cover X=512
    const int z0 = blockIdx.x * CHUNK;

    const long long YX = (long long)Yd * Xd;
    const long long yx = (long long)y * Xd + x;

    // Rolling history: h[k] holds image[z-15+k, y, x..x+3].
    v4f h[Pd];
#pragma unroll
    for (int k = 0; k < Pd; ++k) {
        const int zk = z0 - Pd + k;               // uniform branch (z0 uniform)
        h[k] = (zk >= 0) ? *(const v4f*)(image + (long long)zk * YX + yx)
                         : (v4f){0.f, 0.f, 0.f, 0.f};
    }

    // Pointers that march down z.
    const float* row = image  + (long long)z0 * YX + yx;
    float*       pp  = preds  + (long long)z0 * YX + yx;
    float*       rp  = resids + (long long)z0 * YX + yx;

    // Prefetch band z0 (self + north row + left-edge scalars).
    v4f   self_n  = *(const v4f*)row;
    v4f   north_n = {0.f, 0.f, 0.f, 0.f};
    float sleft_n = 0.f, nleft_n = 0.f;
    if (y > 0) {
        const float* nr = row - Xd;
        north_n = *(const v4f*)nr;
        if (x > 0) nleft_n = nr[-1];
    }
    if (x > 0) sleft_n = row[-1];

#pragma unroll 2
    for (int i = 0; i < CHUNK; ++i) {
        // Consume the prefetched band.
        const v4f   self  = self_n;
        const v4f   north = north_n;
        const float sleft = sleft_n;
        const float nleft = nleft_n;

        // Depth-1 prefetch of band z+1: issue the loads NOW so their latency
        // hides under this band's FMA chain. (y==0 / x==0 threads keep their
        // zero-initialized values — never overwritten.)
        if (i + 1 < CHUNK) {
            const float* nxt = row + YX;
            self_n = *(const v4f*)nxt;
            if (y > 0) {
                const float* nnr = nxt - Xd;
                north_n = *(const v4f*)nnr;
                if (x > 0) nleft_n = nnr[-1];
            }
            if (x > 0) sleft_n = nxt[-1];
        }

        // Per-band weights: address is wave-uniform -> scalar loads.
        const int z = z0 + i;
        const float* wr = weights + z * WDIM;
        const float w3  = wr[3] * (1.0f / 3.0f);
        const float cn  = wr[0] + w3;
        const float cw  = wr[1] + w3;
        const float cnw = wr[2] + w3;

        const v4f west = {sleft, self[0], self[1], self[2]};
        const v4f nwv  = {nleft, north[0], north[1], north[2]};

        v4f p = cn * north + cw * west + cnw * nwv;

        // Spectral predictors from the register window (bands z-15 .. z-1).
#pragma unroll
        for (int k = 0; k < Pd; ++k) {
            const float wk = wr[4 + k];
            p += wk * h[k];
        }

        p[0] = fminf(fmaxf(p[0], MINV), MAXV);
        p[1] = fminf(fmaxf(p[1], MINV), MAXV);
        p[2] = fminf(fmaxf(p[2], MINV), MAXV);
        p[3] = fminf(fmaxf(p[3], MINV), MAXV);

        const v4f r = self - p;

        // Streaming outputs: nontemporal -> don't thrash L2.
        __builtin_nontemporal_store(p, (v4f*)pp);
        __builtin_nontemporal_store(r, (v4f*)rp);

        // Advance the window (constant indices -> stays in registers).
#pragma unroll
        for (int k = 0; k < Pd - 1; ++k) h[k] = h[k + 1];
        h[Pd - 1] = self;

        row += YX;
        pp  += YX;
        rp  += YX;
    }
}

extern "C" void kernel_launch(void* const* d_in, const int* in_sizes, int n_in,
                              void* d_out, int out_size, void* d_ws, size_t ws_size,
                              hipStream_t stream) {
    const float* image   = (const float*)d_in[0];
    const float* weights = (const float*)d_in[1];
    // d_in[2] (local_sums) only feeds the discarded carry — unused.

    float* preds  = (float*)d_out;
    float* resids = (float*)d_out + (long long)Zd * Yd * Xd;

    dim3 block(128, 2, 1);                // 256 threads, full X row per y
    dim3 grid(NCHUNK, Yd / 2, 1);         // 4 z-chunks x 256 y-blocks = 1024
    spec_pred_roll<<<grid, block, 0, stream>>>(image, weights, preds, resids);
}

// Round 2
// 633.078 us; speedup vs baseline: 1.0181x; 1.0181x over previous
//
#include <hip/hip_runtime.h>

// Problem constants (match the JAX reference).
constexpr int Zd = 224;
constexpr int Yd = 512;
constexpr int Xd = 512;
constexpr int Pd = 15;          // spectral predictors
constexpr int WDIM = Pd + 4;    // 19 weights per band
constexpr float MAXV = 32767.0f;   // 2^15 - 1
constexpr float MINV = -32768.0f;  // -2^15

constexpr int NCHUNK = 4;            // z-chunks (parallelism: 4 blocks/CU)
constexpr int CHUNK  = Zd / NCHUNK;  // 56 bands per chunk

typedef float v4f __attribute__((ext_vector_type(4)));

// pred[z,y,x] = clip( cn*north + cw*west + cnw*nw
//                     + sum_{k=0..14} w[4+k]*image[z-15+k,y,x] )
// with cn = w0 + w3/3 etc. (folding the "fourth" predictor).
//
// Rolling-window kernel: thread owns (y, x..x+3), marches z through its
// chunk keeping the previous 15 bands' self-values in registers.
//
// Revision notes (r2):
//  - depth-1 register prefetch of band z+1 (self/north) issued BEFORE band
//    z's FMA chain — loads get a full iteration (~1400 cyc issue across the
//    SIMD's 4 waves) of cover;
//  - NO unroll on the z-loop: unroll-2 (r1) renamed the 60-VGPR window across
//    two iterations and regressed +16 us (register pressure vs the 128-VGPR
//    cap from __launch_bounds__(256,4));
//  - left-edge values (west[0], nw[0]) come from __shfl_up(lane-1) instead of
//    per-iteration global dword loads — each wave spans a contiguous 256-float
//    x-range, so only the wave's lane 0 (x==256 boundary) needs a global
//    dword, predicated to 2 lanes/block. Cuts vmem ops/iter from 6 to 4;
//  - nontemporal stores for preds/resids (streaming, zero reuse) keep L2 for
//    the image reads.
__global__ __launch_bounds__(256, 4) void spec_pred_roll(
    const float* __restrict__ image,
    const float* __restrict__ weights,
    float* __restrict__ preds,
    float* __restrict__ resids)
{
    const int y  = blockIdx.y * 2 + threadIdx.y;   // blockDim = (128, 2)
    const int x  = threadIdx.x * 4;                // 128 threads cover X=512
    const int z0 = blockIdx.x * CHUNK;

    const bool edge    = ((threadIdx.x & 63) == 0);  // wave's lane 0
    const bool edge_ld = edge && (x > 0);            // needs global left dword
    const bool has_n   = (y > 0);

    const long long YX = (long long)Yd * Xd;
    const long long yx = (long long)y * Xd + x;

    // Rolling history: h[k] holds image[z-15+k, y, x..x+3].
    v4f h[Pd];
#pragma unroll
    for (int k = 0; k < Pd; ++k) {
        const int zk = z0 - Pd + k;               // uniform branch (z0 uniform)
        h[k] = (zk >= 0) ? *(const v4f*)(image + (long long)zk * YX + yx)
                         : (v4f){0.f, 0.f, 0.f, 0.f};
    }

    // Pointers that march down z.
    const float* row = image  + (long long)z0 * YX + yx;
    float*       pp  = preds  + (long long)z0 * YX + yx;
    float*       rp  = resids + (long long)z0 * YX + yx;

    // Prefetch band z0 (self + north row + wave-boundary left scalars).
    v4f   self_n  = *(const v4f*)row;
    v4f   north_n = {0.f, 0.f, 0.f, 0.f};
    float sl_n = 0.f, nl_n = 0.f;
    if (has_n) north_n = *(const v4f*)(row - Xd);
    if (edge_ld) {
        sl_n = row[-1];
        if (has_n) nl_n = row[-Xd - 1];
    }

    for (int i = 0; i < CHUNK; ++i) {
        // Consume the prefetched band (register copies, no wait yet).
        const v4f   self  = self_n;
        const v4f   north = north_n;
        const float sl_e  = sl_n;
        const float nl_e  = nl_n;

        // Depth-1 prefetch of band z+1: issue NOW so the latency hides under
        // this band's FMA chain.
        if (i + 1 < CHUNK) {
            const float* nxt = row + YX;
            self_n = *(const v4f*)nxt;
            if (has_n) north_n = *(const v4f*)(nxt - Xd);
            if (edge_ld) {
                sl_n = nxt[-1];
                if (has_n) nl_n = nxt[-Xd - 1];
            }
        }

        // Per-band weights: wave-uniform address -> scalar loads.
        const int z = z0 + i;
        const float* wr = weights + z * WDIM;
        const float w3  = wr[3] * (1.0f / 3.0f);
        const float cn  = wr[0] + w3;
        const float cw  = wr[1] + w3;
        const float cnw = wr[2] + w3;

        // Left neighbors from lane-1 (wave is x-contiguous); wave-boundary
        // lane 0 uses the prefetched global dword (x==0 lanes keep 0.0).
        float sl = __shfl_up(self[3], 1);
        float nl = __shfl_up(north[3], 1);
        if (edge) { sl = sl_e; nl = nl_e; }

        const v4f west = {sl, self[0], self[1], self[2]};
        const v4f nwv  = {nl, north[0], north[1], north[2]};

        v4f p = cn * north + cw * west + cnw * nwv;

        // Spectral predictors from the register window (bands z-15 .. z-1).
#pragma unroll
        for (int k = 0; k < Pd; ++k) {
            p += wr[4 + k] * h[k];
        }

        p[0] = fminf(fmaxf(p[0], MINV), MAXV);
        p[1] = fminf(fmaxf(p[1], MINV), MAXV);
        p[2] = fminf(fmaxf(p[2], MINV), MAXV);
        p[3] = fminf(fmaxf(p[3], MINV), MAXV);

        const v4f r = self - p;

        // Streaming outputs: nontemporal -> don't thrash L2.
        __builtin_nontemporal_store(p, (v4f*)pp);
        __builtin_nontemporal_store(r, (v4f*)rp);

        // Advance the window (constant indices -> stays in registers).
#pragma unroll
        for (int k = 0; k < Pd - 1; ++k) h[k] = h[k + 1];
        h[Pd - 1] = self;

        row += YX;
        pp  += YX;
        rp  += YX;
    }
}

extern "C" void kernel_launch(void* const* d_in, const int* in_sizes, int n_in,
                              void* d_out, int out_size, void* d_ws, size_t ws_size,
                              hipStream_t stream) {
    const float* image   = (const float*)d_in[0];
    const float* weights = (const float*)d_in[1];
    // d_in[2] (local_sums) only feeds the discarded carry — unused.

    float* preds  = (float*)d_out;
    float* resids = (float*)d_out + (long long)Zd * Yd * Xd;

    dim3 block(128, 2, 1);                // 256 threads, full X row per y
    dim3 grid(NCHUNK, Yd / 2, 1);         // 4 z-chunks x 256 y-blocks = 1024
    spec_pred_roll<<<grid, block, 0, stream>>>(image, weights, preds, resids);
}